// Round 7
// baseline (98.263 us; speedup 1.0000x reference)
//
#include <hip/hip_runtime.h>
#include <cstdint>

// (8, 4096, 6) fp32 inputs; scalar fp32 output.
#define NB 8
#define NP 4096
#define NDB 16                     // 2 dirs * 8 batches
#define THREADS 256
#define Q 16                       // queries per thread (CHUNK == NP)
#define SEG 64                     // target split
#define TSEG (NP / SEG)            // 64 targets per block
#define NPAIR (TSEG / 2)           // 32 target pairs

// ws layout (bytes):
//   pk     : float4[16][4096] @ 0      (x,y,z, -0.5|p|^2)          1 MB
//   nrm    : float4[16][4096] @ 1 MB   (unit normal)                1 MB
//   scores : f32 [16][64][4096] @ 2 MB (per-seg max score)         16 MB
//
// Hot loop: packed-fp32 scores for a target PAIR per step:
//   3 x v_pk_fma_f32 + 1 v_max3_f32 = 4 VALU inst / 2 pairs = 2 inst/pair.
// gfx950 VOP3P packed-fp32 needs ALL operands as aligned VGPR pairs (no
// op_sel_hi scalar broadcast for 32-bit packed) -> query scalars are
// duplicated into float2 once before the loop. LDS holds targets
// pair-transposed {x0,x1,y0,y1,z0,z1,w0,w1}: two ds_read_b128 give
// x01/y01/z01/w01 as adjacent pairs, zero repack movs.
// pk_fma halves are IEEE fma => bit-identical to the scalar fmaf chain, so
// finish recovers argmin j by re-running the scalar chain over the winning
// segment, first bit-exact match = lowest j = reference tie semantics.

__device__ inline float2 pk_fma(float2 a, float2 b, float2 c) {
    float2 d;
    asm("v_pk_fma_f32 %0, %1, %2, %3"
        : "=v"(d) : "v"(a), "v"(b), "v"(c));
    return d;
}

__global__ __launch_bounds__(256) void chamfer_prep(
    const float* __restrict__ xyz1, const float* __restrict__ xyz2,
    float4* __restrict__ pk, float4* __restrict__ nrm, float* __restrict__ out)
{
    int gid = blockIdx.x * 256 + threadIdx.x;    // 0..65535 = [c][b][p]
    if (gid == 0) *out = 0.0f;                   // finish is a later dispatch
    int c = gid >> 15;
    const float* src = (c ? xyz2 : xyz1) + (size_t)(gid & 32767) * 6;
    const float2* s2 = (const float2*)src;       // 24B stride: 8-aligned
    float2 a = s2[0], bv = s2[1], cv = s2[2];    // (x,y) (z,nx) (ny,nz)
    float x = a.x, y = a.y, z = bv.x;
    float nx = bv.y, ny = cv.x, nz = cv.y;
    pk[gid] = make_float4(x, y, z, -0.5f * (x * x + y * y + z * z));
    float rn = 1.0f / fmaxf(sqrtf(nx * nx + ny * ny + nz * nz), 1e-12f);
    nrm[gid] = make_float4(nx * rn, ny * rn, nz * rn, 0.0f);
}

__global__ __launch_bounds__(THREADS) void chamfer_argmin(
    const float4* __restrict__ pk, float* __restrict__ scores)
{
    __shared__ float tgt[TSEG * 4];          // pair-transposed, 1 KB

    unsigned int x = blockIdx.x;             // db*SEG + seg
    int seg = x & (SEG - 1);
    int db  = x >> 6;
    int b   = db & 7;
    int dir = db >> 3;
    int qrow = dir * NB + b;
    int trow = (1 - dir) * NB + b;

    // Stage 64 targets pair-transposed: blk {x0,x1,y0,y1,z0,z1,w0,w1}.
    if (threadIdx.x < TSEG) {
        float4 t = pk[(size_t)trow * NP + seg * TSEG + threadIdx.x];
        int blk = threadIdx.x >> 1, h = threadIdx.x & 1;
        float* dstp = tgt + blk * 8 + h;
        dstp[0] = t.x; dstp[2] = t.y; dstp[4] = t.z; dstp[6] = t.w;
    }
    __syncthreads();

    const float4* qp = pk + (size_t)qrow * NP;
    float2 qx2[Q], qy2[Q], qz2[Q];
    float bs[Q];
    #pragma unroll
    for (int i = 0; i < Q; ++i) {
        float4 qv = qp[threadIdx.x + i * THREADS];   // coalesced b128
        qx2[i] = make_float2(qv.x, qv.x);
        qy2[i] = make_float2(qv.y, qv.y);
        qz2[i] = make_float2(qv.z, qv.z);
        bs[i] = -3.4e38f;
    }

    const float4* tp = (const float4*)tgt;
    #pragma unroll 4
    for (int k = 0; k < NPAIR; ++k) {
        float4 r0 = tp[2 * k];               // {x0,x1,y0,y1}
        float4 r1 = tp[2 * k + 1];           // {z0,z1,w0,w1}
        float2 x01 = make_float2(r0.x, r0.y);
        float2 y01 = make_float2(r0.z, r0.w);
        float2 z01 = make_float2(r1.x, r1.y);
        float2 w01 = make_float2(r1.z, r1.w);
        #pragma unroll
        for (int i = 0; i < Q; ++i) {
            float2 s01 = pk_fma(x01, qx2[i],
                          pk_fma(y01, qy2[i],
                           pk_fma(z01, qz2[i], w01)));
            bs[i] = fmaxf(fmaxf(bs[i], s01.x), s01.y);   // v_max3_f32
        }
    }

    float* srow = scores + ((size_t)db * SEG + seg) * NP + threadIdx.x;
    #pragma unroll
    for (int i = 0; i < Q; ++i) srow[i * THREADS] = bs[i];
}

__global__ __launch_bounds__(256) void chamfer_finish(
    const float4* __restrict__ pk, const float4* __restrict__ nrm,
    const float* __restrict__ scores, float* __restrict__ out)
{
    int gid = blockIdx.x * 256 + threadIdx.x;    // 0..65535 = db*NP+q
    int q  = gid & (NP - 1);
    int db = gid >> 12;
    int b  = db & 7;
    int dir = db >> 3;
    int qrow = dir * NB + b;
    int trow = (1 - dir) * NB + b;

    // Winning segment: first strict max over 64 per-seg scores (coalesced).
    const float* sb = scores + (size_t)db * SEG * NP + q;
    float best = -3.4e38f;
    int wseg = 0;
    #pragma unroll
    for (int s = 0; s < SEG; ++s) {
        float v = sb[(size_t)s * NP];
        wseg = (v > best) ? s : wseg;
        best = fmaxf(best, v);
    }

    // Recover argmin index: identical scalar fmaf chain, first bit-exact hit.
    float4 qv = pk[(size_t)qrow * NP + q];
    const float4* tb = pk + (size_t)trow * NP + wseg * TSEG;
    int jf = -1;
    #pragma unroll 8
    for (int k = 0; k < TSEG; ++k) {
        float4 t = tb[k];
        float s = fmaf(t.x, qv.x, fmaf(t.y, qv.y, fmaf(t.z, qv.z, t.w)));
        bool hit = (s == best) && (jf < 0);
        jf = hit ? k : jf;
    }
    int j = wseg * TSEG + (jf < 0 ? 0 : jf);

    // d = |q|^2 - 2 s' ;  |q|^2 = -2 qv.w  ->  d = -2 (qv.w + best)
    float d = fmaxf(-2.0f * (qv.w + best), 0.0f);

    float4 a = nrm[(size_t)qrow * NP + q];
    float4 t = nrm[(size_t)trow * NP + j];
    float dot = a.x * t.x + a.y * t.y + a.z * t.z;
    float nd = fmaf(-2.0f, dot, 2.0f);           // |n1-n2|^2, unit vectors

    float contrib = (d + nd) * (1.0f / 32768.0f);
    for (int off = 32; off > 0; off >>= 1)
        contrib += __shfl_down(contrib, off, 64);
    __shared__ float wsum[4];
    if ((threadIdx.x & 63) == 0) wsum[threadIdx.x >> 6] = contrib;
    __syncthreads();
    if (threadIdx.x == 0)
        atomicAdd(out, wsum[0] + wsum[1] + wsum[2] + wsum[3]);
}

extern "C" void kernel_launch(void* const* d_in, const int* in_sizes, int n_in,
                              void* d_out, int out_size, void* d_ws, size_t ws_size,
                              hipStream_t stream) {
    const float* xyz1 = (const float*)d_in[0];
    const float* xyz2 = (const float*)d_in[1];
    char* ws = (char*)d_ws;
    float4* pk     = (float4*)(ws);
    float4* nrm    = (float4*)(ws + (1u << 20));
    float*  scores = (float*)(ws + (2u << 20));

    chamfer_prep<<<256, 256, 0, stream>>>(xyz1, xyz2, pk, nrm, (float*)d_out);
    chamfer_argmin<<<NDB * SEG, THREADS, 0, stream>>>(pk, scores);
    chamfer_finish<<<(NDB * NP) / 256, 256, 0, stream>>>(pk, nrm, scores, (float*)d_out);
}